// Round 1
// baseline (324.275 us; speedup 1.0000x reference)
//
#include <hip/hip_runtime.h>
#include <math.h>

#define NDIN 128
#define NHID 128
#define NDOUT 64

typedef _Float16 half2_t __attribute__((ext_vector_type(2)));
typedef _Float16 half4_t __attribute__((ext_vector_type(4)));
typedef _Float16 half8_t __attribute__((ext_vector_type(8)));
typedef float    float4v __attribute__((ext_vector_type(4)));

__device__ __forceinline__ float gelu_exact(float x) {
    return 0.5f * x * (1.0f + erff(x * 0.70710678118654752f));
}

// ---------------- prep0: 3x weight transpose+cast, zero count & done ----------------
// W[K][N] fp32 -> Wt[N][K] fp16, 32x32 LDS tiles.

__device__ void wtrans_tile(const float* __restrict__ W, _Float16* __restrict__ Wt,
                            int K, int N, int bx, int by) {
    __shared__ float tile[32][33];
    int tx = threadIdx.x & 31, ty = threadIdx.x >> 5;   // ty 0..7
    for (int i = 0; i < 32; i += 8) {
        int k = by * 32 + ty + i, nn = bx * 32 + tx;
        tile[ty + i][tx] = (k < K && nn < N) ? W[(size_t)k * N + nn] : 0.f;
    }
    __syncthreads();
    for (int i = 0; i < 32; i += 8) {
        int nn = bx * 32 + ty + i, k = by * 32 + tx;
        if (nn < N && k < K) Wt[(size_t)nn * K + k] = (_Float16)tile[tx][ty + i];
    }
}

// blocks: [0,16) W1; [16,32) W2; [32,40) W3; [40,40+NB) zero count (+done in block 40)
__global__ __launch_bounds__(256) void prep0_kernel(
    const float* __restrict__ W1, _Float16* __restrict__ W1t,
    const float* __restrict__ W2, _Float16* __restrict__ W2t,
    const float* __restrict__ W3, _Float16* __restrict__ W3t,
    int* __restrict__ count, int* __restrict__ done, int n) {
    int b = blockIdx.x;
    if (b < 16) {
        wtrans_tile(W1, W1t, NDIN, NHID, b & 3, b >> 2);
    } else if (b < 32) {
        wtrans_tile(W2, W2t, NHID, NHID, (b - 16) & 3, (b - 16) >> 2);
    } else if (b < 40) {
        wtrans_tile(W3, W3t, NHID, NDOUT, (b - 32) & 1, (b - 32) >> 1);
    } else {
        int z = b - 40;
        int i = z * 256 + threadIdx.x;
        if (i < n) count[i] = 0;
        if (z == 0 && threadIdx.x < 64) done[threadIdx.x] = 0;  // done[0]=arrive ctr, done[1]=flag
    }
}

// ---------------- degree count ----------------

__global__ void count_kernel(const int* __restrict__ dst, int* __restrict__ count, int E) {
    int e = blockIdx.x * blockDim.x + threadIdx.x;
    if (e < E) atomicAdd(&count[dst[e]], 1);
}

// ---------------- merged reduce + partial-scan + per-block scan + dinv ----------------
// Replaces the old reduce_scanp + scan_blocks pair (one fewer launch, one fewer count[]
// pass). Last-arriving block scans the partials and raises done[1]; other blocks spin on
// it (device-scope atomics only — safe under XCD non-coherence). Deadlock-free for ANY
// dispatch order: the scanner is the last block to finish phase 1, so whenever a block
// spins, its flag-setter is already executing. nb <= 256 required (nb = 196 here).

__global__ __launch_bounds__(256) void reduce_scan_kernel(
    const int* __restrict__ count, int* __restrict__ blocksum, int* __restrict__ blockoff,
    int* __restrict__ rowptr, float* __restrict__ dinv, int* __restrict__ done,
    int nb, int n) {
    __shared__ int s[256];
    __shared__ int flag;
    __shared__ int boff_s;
    int t = threadIdx.x;
    int i = blockIdx.x * 256 + t;
    int v = (i < n) ? count[i] : 0;
    s[t] = v;
    __syncthreads();
    for (int off = 128; off > 0; off >>= 1) {
        if (t < off) s[t] += s[t + off];
        __syncthreads();
    }
    if (t == 0) {
        atomicExch(&blocksum[blockIdx.x], s[0]);
        __threadfence();
        int old = atomicAdd(&done[0], 1);
        flag = (old == nb - 1) ? 1 : 0;
    }
    __syncthreads();
    if (flag) {  // last block: scan the per-block partials, publish offsets + flag
        __threadfence();
        int pv = (t < nb) ? atomicAdd(&blocksum[t], 0) : 0;
        s[t] = pv;
        __syncthreads();
        for (int off = 1; off < 256; off <<= 1) {
            int u = (t >= off) ? s[t - off] : 0;
            __syncthreads();
            s[t] += u;
            __syncthreads();
        }
        if (t < nb) atomicExch(&blockoff[t], s[t] - pv);   // exclusive
        if (t == 255) rowptr[n] = s[255];                  // grand total
        __threadfence();
        if (t == 0) atomicExch(&done[1], 1);
    } else if (t == 0) {
        while (atomicAdd(&done[1], 0) == 0) __builtin_amdgcn_s_sleep(2);
        __threadfence();
    }
    __syncthreads();
    if (t == 0) boff_s = atomicAdd(&blockoff[blockIdx.x], 0);  // atomic read: coherent
    s[t] = v;
    __syncthreads();
    for (int off = 1; off < 256; off <<= 1) {
        int u = (t >= off) ? s[t - off] : 0;
        __syncthreads();
        s[t] += u;
        __syncthreads();
    }
    if (i < n) {
        rowptr[i] = boff_s + s[t] - v;
        dinv[i] = rsqrtf((float)(v + 1));
    }
}

// ---------------- shared GEMM phase: T[64,BN] tile = lds_a[64,128] @ Bt^T ----------------
// B operand read straight from global: the fp16 weight is 32 KB -> L1-resident after the
// first touch per CU (every block reads the same bytes). No lds_bt => kernel LDS is
// 17.4 KB, so fused-in gather/scatter work keeps high occupancy (avoids R5's 52 KB trap).

template <int BN>
__device__ __forceinline__ void gemm_phaseB(
    const _Float16 (*lds_a)[136], const _Float16* __restrict__ Bt,
    _Float16* __restrict__ T, int bm, int M) {
    int tid = threadIdx.x;
    int wave = tid >> 6, lane = tid & 63;
    int m = lane & 15, quad = lane >> 4;
    const int NT = BN / 16;
    float4v acc[NT];
#pragma unroll
    for (int nt = 0; nt < NT; nt++) acc[nt] = (float4v){0.f, 0.f, 0.f, 0.f};
    int arow = (wave << 4) + m;
#pragma unroll
    for (int kc = 0; kc < 128; kc += 32) {
        half8_t a = *(const half8_t*)&lds_a[arow][kc + quad * 8];
#pragma unroll
        for (int nt = 0; nt < NT; nt++) {
            half8_t b = *(const half8_t*)&Bt[(size_t)(nt * 16 + m) * 128 + kc + quad * 8];
            acc[nt] = __builtin_amdgcn_mfma_f32_16x16x32_f16(a, b, acc[nt], 0, 0, 0);
        }
    }
#pragma unroll
    for (int nt = 0; nt < NT; nt++) {
#pragma unroll
        for (int r = 0; r < 4; r++) {
            int grow = bm + (wave << 4) + (quad << 2) + r;
            if (grow < M) T[(size_t)grow * BN + nt * 16 + m] = (_Float16)acc[nt][r];
        }
    }
}

// ---------------- agg body for one node, F=128 (R4 readlane formulation) ----------------

__device__ __forceinline__ half2_t agg_node128(
    const half2_t* __restrict__ t2, const int* __restrict__ rowptr,
    const int2* __restrict__ adj, const float* __restrict__ dinv,
    const float* __restrict__ bias, int node, int lane) {
    float wself = dinv[node];
    wself *= wself;
    half2_t v = t2[(size_t)node * 64 + lane];
    float accx = wself * (float)v[0], accy = wself * (float)v[1];
    int beg = rowptr[node], end = rowptr[node + 1];
    for (int e0 = beg; e0 < end; e0 += 64) {
        int rem = end - e0;
        int j = 0; float w = 0.f;
        if (lane < rem) {
            int2 ed = adj[e0 + lane];
            j = ed.x; w = __int_as_float(ed.y);
        }
        int cnt = rem < 64 ? rem : 64;
        for (int c = 0; c < cnt; c += 16) {
#pragma unroll
            for (int i = 0; i < 16; i++) {
                int jj = __builtin_amdgcn_readlane(j, c + i);
                float ww = __int_as_float(
                    __builtin_amdgcn_readlane(__float_as_int(w), c + i));
                half2_t u = t2[(size_t)jj * 64 + lane];
                accx += ww * (float)u[0];
                accy += ww * (float)u[1];
            }
        }
    }
    float2 b = ((const float2*)bias)[lane];
    accx = gelu_exact(accx + b.x);
    accy = gelu_exact(accy + b.y);
    half2_t o; o[0] = (_Float16)accx; o[1] = (_Float16)accy;
    return o;
}

// ---------------- fused CSR-fill (blocks [0,fillblocks)) || gemm1 (rest) ----------------
// fill depends on the scan; gemm1 only on prep0 -> they are independent, so run them as
// disjoint block ranges of ONE launch to overlap the scatter-latency-bound fill with the
// compute/BW-bound GEMM. LDS is 17.4 KB so fill blocks keep ~6 blocks/CU (not R5's 3).

__global__ __launch_bounds__(256) void fill_gemm1_kernel(
    const int* __restrict__ src, const int* __restrict__ dst,
    const float* __restrict__ dinv, const int* __restrict__ rowptr,
    int* __restrict__ count, int2* __restrict__ adj, int E,
    const float* __restrict__ x, const _Float16* __restrict__ W1t,
    _Float16* __restrict__ T, int M, int fillblocks) {
    __shared__ _Float16 lds_a[64][136];
    int b = blockIdx.x;
    if (b < fillblocks) {                       // ---- CSR fill ----
        int e = b * 256 + threadIdx.x;
        if (e >= E) return;
        int s = src[e], d = dst[e];
        int slot = atomicSub(&count[d], 1) - 1;
        int p = rowptr[d] + slot;
        adj[p] = make_int2(s, __float_as_int(dinv[s] * dinv[d]));
        return;
    }
    // ---- gemm1: stage x (fp32 -> fp16) then MFMA ----
    int bm = (b - fillblocks) * 64;
    int tid = threadIdx.x;
#pragma unroll
    for (int j = 0; j < 8; j++) {
        int c = tid + j * 256;
        int r = c >> 5, col = (c & 31) << 2;
        int grow = bm + r;
        float4 v = make_float4(0.f, 0.f, 0.f, 0.f);
        if (grow < M) v = *(const float4*)(x + (size_t)grow * 128 + col);
        half4_t h;
        h[0] = (_Float16)v.x; h[1] = (_Float16)v.y;
        h[2] = (_Float16)v.z; h[3] = (_Float16)v.w;
        *(half4_t*)&lds_a[r][col] = h;
    }
    __syncthreads();
    gemm_phaseB<128>(lds_a, W1t, T, bm, M);
}

// ---------------- fused agg_i -> gemm_{i+1} ----------------
// A gemm tile's 64 A-rows ARE 64 nodes' agg outputs: 4 waves x 16 nodes sequential,
// results land directly in lds_a (no hbuf round trip: saves 25.6 MB traffic + a launch
// per pair). launch_bounds(256,4) pins >=4 blocks/CU so all 782 blocks are co-resident:
// gather phase has 16 waves/CU x 16-deep MLP = 256 outstanding rows/CU (Little's law
// needs ~18 at 3.2 TB/s, 900 cyc) — not concurrency-starved.

template <int BN>
__global__ __launch_bounds__(256, 4) void agg_gemm_kernel(
    const _Float16* __restrict__ t, const int* __restrict__ rowptr,
    const int2* __restrict__ adj, const float* __restrict__ dinv,
    const float* __restrict__ bias, const _Float16* __restrict__ Bt,
    _Float16* __restrict__ T, int M) {
    __shared__ _Float16 lds_a[64][136];
    int tid = threadIdx.x;
    int wave = tid >> 6, lane = tid & 63;
    int bm = blockIdx.x * 64;
    const half2_t* t2 = (const half2_t*)t;
#pragma unroll 1
    for (int p = 0; p < 16; p++) {
        int r = (wave << 4) + p;
        int node = bm + r;
        half2_t o;
        o[0] = (_Float16)0.f; o[1] = (_Float16)0.f;
        if (node < M) o = agg_node128(t2, rowptr, adj, dinv, bias, node, lane);
        *(half2_t*)&lds_a[r][lane << 1] = o;   // 4B/lane, 2 lanes/bank: conflict-free
    }
    __syncthreads();
    gemm_phaseB<BN>(lds_a, Bt, T, bm, M);
}

// ---------------- final aggregation (unchanged R4 readlane formulation) ----------------
// out[i] = sum_e w_e*t[src_e] + dinv[i]^2*t[i] + b ; t fp16, fp32 accum, fp32 out.

template <int F, bool DOGELU, bool OUTF16>
__global__ __launch_bounds__(256) void agg_kernel(
    const _Float16* __restrict__ t, const int* __restrict__ rowptr,
    const int2* __restrict__ adj, const float* __restrict__ dinv,
    const float* __restrict__ bias, void* __restrict__ outp, int n) {
    int node = (int)((blockIdx.x * blockDim.x + threadIdx.x) >> 6);
    int lane = threadIdx.x & 63;
    if (node >= n) return;   // wave-uniform exit

    float wself = dinv[node];
    wself *= wself;
    int beg = rowptr[node];
    int end = rowptr[node + 1];

    if (F == 128) {
        const half2_t* t2 = (const half2_t*)t;
        half2_t v = t2[(size_t)node * 64 + lane];
        float accx = wself * (float)v[0], accy = wself * (float)v[1];
        for (int e0 = beg; e0 < end; e0 += 64) {
            int rem = end - e0;
            int j = 0; float w = 0.f;
            if (lane < rem) {
                int2 ed = adj[e0 + lane];
                j = ed.x; w = __int_as_float(ed.y);
            }
            int cnt = rem < 64 ? rem : 64;
            for (int c = 0; c < cnt; c += 16) {
#pragma unroll
                for (int i = 0; i < 16; i++) {
                    int jj = __builtin_amdgcn_readlane(j, c + i);
                    float ww = __int_as_float(
                        __builtin_amdgcn_readlane(__float_as_int(w), c + i));
                    half2_t u = t2[(size_t)jj * 64 + lane];
                    accx += ww * (float)u[0];
                    accy += ww * (float)u[1];
                }
            }
        }
        float2 b = ((const float2*)bias)[lane];
        accx += b.x; accy += b.y;
        if (DOGELU) { accx = gelu_exact(accx); accy = gelu_exact(accy); }
        if (OUTF16) {
            half2_t o; o[0] = (_Float16)accx; o[1] = (_Float16)accy;
            ((half2_t*)outp)[(size_t)node * 64 + lane] = o;
        } else {
            float2 o; o.x = accx; o.y = accy;
            ((float2*)outp)[(size_t)node * 64 + lane] = o;
        }
    } else {  // F == 64
        float acc = wself * (float)t[(size_t)node * 64 + lane];
        for (int e0 = beg; e0 < end; e0 += 64) {
            int rem = end - e0;
            int j = 0; float w = 0.f;
            if (lane < rem) {
                int2 ed = adj[e0 + lane];
                j = ed.x; w = __int_as_float(ed.y);
            }
            int cnt = rem < 64 ? rem : 64;
            for (int c = 0; c < cnt; c += 16) {
#pragma unroll
                for (int i = 0; i < 16; i++) {
                    int jj = __builtin_amdgcn_readlane(j, c + i);
                    float ww = __int_as_float(
                        __builtin_amdgcn_readlane(__float_as_int(w), c + i));
                    acc += ww * (float)t[(size_t)jj * 64 + lane];
                }
            }
        }
        acc += bias[lane];
        if (DOGELU) acc = gelu_exact(acc);
        if (OUTF16) ((_Float16*)outp)[(size_t)node * 64 + lane] = (_Float16)acc;
        else        ((float*)outp)[(size_t)node * 64 + lane] = acc;
    }
}

// ---------------- launch ----------------

extern "C" void kernel_launch(void* const* d_in, const int* in_sizes, int n_in,
                              void* d_out, int out_size, void* d_ws, size_t ws_size,
                              hipStream_t stream) {
    const float* x  = (const float*)d_in[0];
    const int* edge = (const int*)d_in[1];
    const float* W1 = (const float*)d_in[2];
    const float* b1 = (const float*)d_in[3];
    const float* W2 = (const float*)d_in[4];
    const float* b2 = (const float*)d_in[5];
    const float* W3 = (const float*)d_in[6];
    const float* b3 = (const float*)d_in[7];
    float* out = (float*)d_out;

    const int N = in_sizes[0] / NDIN;       // 50000
    const int E = in_sizes[1] / 2;          // 800000
    const int* src = edge;
    const int* dst = edge + E;
    const int NB = (N + 255) / 256;         // 196 (must be <= 256)

    // workspace carve-out (256B aligned)
    char* p = (char*)d_ws;
    auto alloc = [&](size_t bytes) {
        char* q = p;
        p += (bytes + 255) & ~(size_t)255;
        return q;
    };
    int*       count    = (int*)alloc((size_t)N * 4);
    int*       rowptr   = (int*)alloc((size_t)(N + 1) * 4);
    int*       blocksum = (int*)alloc((size_t)NB * 4);
    int*       blockoff = (int*)alloc((size_t)NB * 4);
    int*       done     = (int*)alloc(256);
    float*     dinv     = (float*)alloc((size_t)N * 4);
    int2*      adj      = (int2*)alloc((size_t)E * 8);
    _Float16*  W1t      = (_Float16*)alloc((size_t)NHID * NDIN * 2);
    _Float16*  W2t      = (_Float16*)alloc((size_t)NHID * NHID * 2);
    _Float16*  W3t      = (_Float16*)alloc((size_t)NDOUT * NHID * 2);
    _Float16*  tbuf     = (_Float16*)alloc((size_t)N * NHID * 2);
    _Float16*  hbuf     = (_Float16*)alloc((size_t)N * NHID * 2);

    dim3 blk(256);
    int mtiles = (N + 63) / 64;             // 782
    int eblocks = (E + 255) / 256;          // 3125
    int agg_blocks = (N + 3) / 4;           // 12500

    // 1. weight transpose+cast + zero count/done
    prep0_kernel<<<40 + NB, blk, 0, stream>>>(W1, W1t, W2, W2t, W3, W3t, count, done, N);
    // 2. degree count
    count_kernel<<<eblocks, blk, 0, stream>>>(dst, count, E);
    // 3. merged reduce + scan + dinv (spin on device-scope flag)
    reduce_scan_kernel<<<NB, blk, 0, stream>>>(count, blocksum, blockoff, rowptr,
                                               dinv, done, NB, N);
    // 4. CSR fill || gemm1 (independent: fill needs scan, gemm1 only needs W1t)
    fill_gemm1_kernel<<<eblocks + mtiles, blk, 0, stream>>>(
        src, dst, dinv, rowptr, count, adj, E, x, W1t, tbuf, N, eblocks);
    // 5. agg1 (gelu,b1) fused with gemm2 -> hbuf
    agg_gemm_kernel<128><<<mtiles, blk, 0, stream>>>(tbuf, rowptr, adj, dinv, b1,
                                                     W2t, hbuf, N);
    // 6. agg2 (gelu,b2) fused with gemm3 -> tbuf (N x 64 fp16)
    agg_gemm_kernel<64><<<mtiles, blk, 0, stream>>>(hbuf, rowptr, adj, dinv, b2,
                                                    W3t, tbuf, N);
    // 7. final agg (no gelu, fp32 out)
    agg_kernel<64, false, false><<<agg_blocks, blk, 0, stream>>>(tbuf, rowptr, adj,
                                                                 dinv, b3, out, N);
}

// Round 2
// 289.483 us; speedup vs baseline: 1.1202x; 1.1202x over previous
//
#include <hip/hip_runtime.h>
#include <math.h>

#define NDIN 128
#define NHID 128
#define NDOUT 64

typedef _Float16 half2_t __attribute__((ext_vector_type(2)));
typedef _Float16 half4_t __attribute__((ext_vector_type(4)));
typedef _Float16 half8_t __attribute__((ext_vector_type(8)));
typedef float    float4v __attribute__((ext_vector_type(4)));

__device__ __forceinline__ float gelu_exact(float x) {
    return 0.5f * x * (1.0f + erff(x * 0.70710678118654752f));
}

// ---------------- prep0: 3x weight transpose+cast, zero count & done ----------------
// W[K][N] fp32 -> Wt[N][K] fp16, 32x32 LDS tiles.

__device__ void wtrans_tile(const float* __restrict__ W, _Float16* __restrict__ Wt,
                            int K, int N, int bx, int by) {
    __shared__ float tile[32][33];
    int tx = threadIdx.x & 31, ty = threadIdx.x >> 5;   // ty 0..7
    for (int i = 0; i < 32; i += 8) {
        int k = by * 32 + ty + i, nn = bx * 32 + tx;
        tile[ty + i][tx] = (k < K && nn < N) ? W[(size_t)k * N + nn] : 0.f;
    }
    __syncthreads();
    for (int i = 0; i < 32; i += 8) {
        int nn = bx * 32 + ty + i, k = by * 32 + tx;
        if (nn < N && k < K) Wt[(size_t)nn * K + k] = (_Float16)tile[tx][ty + i];
    }
}

// blocks: [0,16) W1; [16,32) W2; [32,40) W3; [40,40+NB) zero count (+done in block 40)
__global__ __launch_bounds__(256) void prep0_kernel(
    const float* __restrict__ W1, _Float16* __restrict__ W1t,
    const float* __restrict__ W2, _Float16* __restrict__ W2t,
    const float* __restrict__ W3, _Float16* __restrict__ W3t,
    int* __restrict__ count, int* __restrict__ done, int n) {
    int b = blockIdx.x;
    if (b < 16) {
        wtrans_tile(W1, W1t, NDIN, NHID, b & 3, b >> 2);
    } else if (b < 32) {
        wtrans_tile(W2, W2t, NHID, NHID, (b - 16) & 3, (b - 16) >> 2);
    } else if (b < 40) {
        wtrans_tile(W3, W3t, NHID, NDOUT, (b - 32) & 1, (b - 32) >> 1);
    } else {
        int z = b - 40;
        int i = z * 256 + threadIdx.x;
        if (i < n) count[i] = 0;
        if (z == 0 && threadIdx.x < 64) done[threadIdx.x] = 0;  // done[0]=arrive, done[1]=flag
    }
}

// ---------------- degree count ----------------

__global__ void count_kernel(const int* __restrict__ dst, int* __restrict__ count, int E) {
    int e = blockIdx.x * blockDim.x + threadIdx.x;
    if (e < E) atomicAdd(&count[dst[e]], 1);
}

// ---------------- merged reduce + partial-scan + per-block scan + dinv ----------------
// Last-arriving block scans the partials and raises done[1]; other blocks spin on it
// (device-scope atomics only — safe under XCD non-coherence). Deadlock-free for ANY
// dispatch order: the scanner is the last block to finish phase 1, so whenever a block
// spins, its flag-setter is already executing. nb <= 256 required (nb = 196 here).

__global__ __launch_bounds__(256) void reduce_scan_kernel(
    const int* __restrict__ count, int* __restrict__ blocksum, int* __restrict__ blockoff,
    int* __restrict__ rowptr, float* __restrict__ dinv, int* __restrict__ done,
    int nb, int n) {
    __shared__ int s[256];
    __shared__ int flag;
    __shared__ int boff_s;
    int t = threadIdx.x;
    int i = blockIdx.x * 256 + t;
    int v = (i < n) ? count[i] : 0;
    s[t] = v;
    __syncthreads();
    for (int off = 128; off > 0; off >>= 1) {
        if (t < off) s[t] += s[t + off];
        __syncthreads();
    }
    if (t == 0) {
        atomicExch(&blocksum[blockIdx.x], s[0]);
        __threadfence();
        int old = atomicAdd(&done[0], 1);
        flag = (old == nb - 1) ? 1 : 0;
    }
    __syncthreads();
    if (flag) {  // last block: scan the per-block partials, publish offsets + flag
        __threadfence();
        int pv = (t < nb) ? atomicAdd(&blocksum[t], 0) : 0;
        s[t] = pv;
        __syncthreads();
        for (int off = 1; off < 256; off <<= 1) {
            int u = (t >= off) ? s[t - off] : 0;
            __syncthreads();
            s[t] += u;
            __syncthreads();
        }
        if (t < nb) atomicExch(&blockoff[t], s[t] - pv);   // exclusive
        if (t == 255) rowptr[n] = s[255];                  // grand total
        __threadfence();
        if (t == 0) atomicExch(&done[1], 1);
    } else if (t == 0) {
        while (atomicAdd(&done[1], 0) == 0) __builtin_amdgcn_s_sleep(2);
        __threadfence();
    }
    __syncthreads();
    if (t == 0) boff_s = atomicAdd(&blockoff[blockIdx.x], 0);  // atomic read: coherent
    s[t] = v;
    __syncthreads();
    for (int off = 1; off < 256; off <<= 1) {
        int u = (t >= off) ? s[t - off] : 0;
        __syncthreads();
        s[t] += u;
        __syncthreads();
    }
    if (i < n) {
        rowptr[i] = boff_s + s[t] - v;
        dinv[i] = rsqrtf((float)(v + 1));
    }
}

// ---------------- CSR fill (standalone: zero LDS -> full occupancy; R0-proven) ----------
// R1 post-mortem: fusing this with gemm1 cost ~20 us (latency-bound scatter got no
// overlap, mutual L2 interference). Keep standalone.

__global__ void fill_kernel(const int* __restrict__ src, const int* __restrict__ dst,
                            const float* __restrict__ dinv, const int* __restrict__ rowptr,
                            int* __restrict__ count, int2* __restrict__ adj, int E) {
    int e = blockIdx.x * blockDim.x + threadIdx.x;
    if (e >= E) return;
    int s = src[e], d = dst[e];
    int slot = atomicSub(&count[d], 1) - 1;
    int p = rowptr[d] + slot;
    adj[p] = make_int2(s, __float_as_int(dinv[s] * dinv[d]));
}

// ---------------- fp16 MFMA GEMM (R0-proven, layer-1 only): T = A @ Bt^T ----------------
// K fixed = 128, staged whole; 256 threads = 4 waves; wave w does rows [bm+16w,+16).

template <int BN, bool AF16>
__global__ __launch_bounds__(256) void gemm_mfma(
    const void* __restrict__ Aptr, const _Float16* __restrict__ Bt,
    _Float16* __restrict__ T, int M) {
    __shared__ _Float16 lds_a[64][136];
    __shared__ _Float16 lds_bt[BN][136];
    const int K = 128;
    int tid = threadIdx.x;
    int bm = blockIdx.x * 64;
    int wave = tid >> 6, lane = tid & 63;
    int m = lane & 15, quad = lane >> 4;

    if (AF16) {
        const _Float16* A = (const _Float16*)Aptr;
#pragma unroll
        for (int j = 0; j < 4; j++) {
            int c = tid + j * 256;
            int r = c >> 4, col = (c & 15) << 3;
            int grow = bm + r;
            uint4 v = make_uint4(0, 0, 0, 0);
            if (grow < M) v = *(const uint4*)(A + (size_t)grow * K + col);
            *(uint4*)&lds_a[r][col] = v;
        }
    } else {
        const float* A = (const float*)Aptr;
#pragma unroll
        for (int j = 0; j < 8; j++) {
            int c = tid + j * 256;
            int r = c >> 5, col = (c & 31) << 2;
            int grow = bm + r;
            float4 v = make_float4(0.f, 0.f, 0.f, 0.f);
            if (grow < M) v = *(const float4*)(A + (size_t)grow * K + col);
            half4_t h;
            h[0] = (_Float16)v.x; h[1] = (_Float16)v.y;
            h[2] = (_Float16)v.z; h[3] = (_Float16)v.w;
            *(half4_t*)&lds_a[r][col] = h;
        }
    }
    {
        const int chunks = BN * K / 8;
        for (int c = tid; c < chunks; c += 256) {
            int r = c >> 4, col = (c & 15) << 3;
            *(uint4*)&lds_bt[r][col] = *(const uint4*)(Bt + (size_t)r * K + col);
        }
    }
    __syncthreads();

    const int NT = BN / 16;
    float4v acc[NT];
#pragma unroll
    for (int nt = 0; nt < NT; nt++) acc[nt] = (float4v){0.f, 0.f, 0.f, 0.f};

    int arow = (wave << 4) + m;
#pragma unroll
    for (int kc = 0; kc < K; kc += 32) {
        half8_t a = *(const half8_t*)&lds_a[arow][kc + quad * 8];
#pragma unroll
        for (int nt = 0; nt < NT; nt++) {
            half8_t b = *(const half8_t*)&lds_bt[nt * 16 + m][kc + quad * 8];
            acc[nt] = __builtin_amdgcn_mfma_f32_16x16x32_f16(a, b, acc[nt], 0, 0, 0);
        }
    }
#pragma unroll
    for (int nt = 0; nt < NT; nt++) {
#pragma unroll
        for (int r = 0; r < 4; r++) {
            int grow = bm + (wave << 4) + (quad << 2) + r;
            if (grow < M) T[(size_t)grow * BN + nt * 16 + m] = (_Float16)acc[nt][r];
        }
    }
}

// ---------------- agg body for one node, F=128 (R4 readlane formulation) ----------------

__device__ __forceinline__ half2_t agg_node128(
    const half2_t* __restrict__ t2, const int* __restrict__ rowptr,
    const int2* __restrict__ adj, const float* __restrict__ dinv,
    const float* __restrict__ bias, int node, int lane) {
    float wself = dinv[node];
    wself *= wself;
    half2_t v = t2[(size_t)node * 64 + lane];
    float accx = wself * (float)v[0], accy = wself * (float)v[1];
    int beg = rowptr[node], end = rowptr[node + 1];
    for (int e0 = beg; e0 < end; e0 += 64) {
        int rem = end - e0;
        int j = 0; float w = 0.f;
        if (lane < rem) {
            int2 ed = adj[e0 + lane];
            j = ed.x; w = __int_as_float(ed.y);
        }
        int cnt = rem < 64 ? rem : 64;
        for (int c = 0; c < cnt; c += 16) {
#pragma unroll
            for (int i = 0; i < 16; i++) {
                int jj = __builtin_amdgcn_readlane(j, c + i);
                float ww = __int_as_float(
                    __builtin_amdgcn_readlane(__float_as_int(w), c + i));
                half2_t u = t2[(size_t)jj * 64 + lane];
                accx += ww * (float)u[0];
                accy += ww * (float)u[1];
            }
        }
    }
    float2 b = ((const float2*)bias)[lane];
    accx = gelu_exact(accx + b.x);
    accy = gelu_exact(accy + b.y);
    half2_t o; o[0] = (_Float16)accx; o[1] = (_Float16)accy;
    return o;
}

// ---------------- fused agg_i -> gemm_{i+1}, 16-row tiles (R1 post-mortem fix) ----------
// R1's 64-row fusion starved the gather: grid 782 -> 3 blocks/CU -> 192 outstanding
// rows/CU -> 1.48 TB/s (vs 3.2 floor). This version: N/16 = 3125 blocks, 4 waves each,
// each wave aggs 4 nodes -> thread-capped 8 blocks/CU = 32 gather-waves/CU x 16
// outstanding = 512 rows in flight, identical to the standalone agg. LDS 4.4 KB,
// VGPR <= 64 (acc is only NT<=2 fragments) so full 32-wave occupancy holds.
// GEMM phase: 16xBN tile, wave w covers cols [w*BN/4, (w+1)*BN/4); B from global
// (32 KB weight, L1-resident). Saves the 25.6 MB hbuf round-trip + a launch per pair.

template <int BN>
__global__ __launch_bounds__(256) void agg_gemm16_kernel(
    const _Float16* __restrict__ t, const int* __restrict__ rowptr,
    const int2* __restrict__ adj, const float* __restrict__ dinv,
    const float* __restrict__ bias, const _Float16* __restrict__ Bt,
    _Float16* __restrict__ T, int M) {
    __shared__ _Float16 lds_a[16][136];
    int tid = threadIdx.x;
    int wave = tid >> 6, lane = tid & 63;
    int bm = blockIdx.x * 16;
    const half2_t* t2 = (const half2_t*)t;
#pragma unroll 1
    for (int p = 0; p < 4; p++) {
        int r = (wave << 2) + p;
        int node = bm + r;
        half2_t o;
        o[0] = (_Float16)0.f; o[1] = (_Float16)0.f;
        if (node < M) o = agg_node128(t2, rowptr, adj, dinv, bias, node, lane);
        *(half2_t*)&lds_a[r][lane << 1] = o;   // 4B/lane: conflict-free
    }
    __syncthreads();

    int m = lane & 15, quad = lane >> 4;
    const int NT = BN / 64;                    // fragments per wave: 128->2, 64->1
    float4v acc[NT];
#pragma unroll
    for (int nt = 0; nt < NT; nt++) acc[nt] = (float4v){0.f, 0.f, 0.f, 0.f};
#pragma unroll
    for (int kc = 0; kc < 128; kc += 32) {
        half8_t a = *(const half8_t*)&lds_a[m][kc + quad * 8];
#pragma unroll
        for (int nt = 0; nt < NT; nt++) {
            int col = wave * (BN / 4) + nt * 16 + m;
            half8_t b = *(const half8_t*)&Bt[(size_t)col * 128 + kc + quad * 8];
            acc[nt] = __builtin_amdgcn_mfma_f32_16x16x32_f16(a, b, acc[nt], 0, 0, 0);
        }
    }
#pragma unroll
    for (int nt = 0; nt < NT; nt++) {
#pragma unroll
        for (int r = 0; r < 4; r++) {
            int grow = bm + (quad << 2) + r;
            int col = wave * (BN / 4) + nt * 16 + m;
            if (grow < M) T[(size_t)grow * BN + col] = (_Float16)acc[nt][r];
        }
    }
}

// ---------------- final aggregation (R4 readlane formulation, R0-proven) ----------------
// out[i] = sum_e w_e*t[src_e] + dinv[i]^2*t[i] + b ; t fp16, fp32 accum.

template <int F, bool DOGELU, bool OUTF16>
__global__ __launch_bounds__(256) void agg_kernel(
    const _Float16* __restrict__ t, const int* __restrict__ rowptr,
    const int2* __restrict__ adj, const float* __restrict__ dinv,
    const float* __restrict__ bias, void* __restrict__ outp, int n) {
    int node = (int)((blockIdx.x * blockDim.x + threadIdx.x) >> 6);
    int lane = threadIdx.x & 63;
    if (node >= n) return;   // wave-uniform exit

    float wself = dinv[node];
    wself *= wself;
    int beg = rowptr[node];
    int end = rowptr[node + 1];

    if (F == 128) {
        const half2_t* t2 = (const half2_t*)t;
        half2_t v = t2[(size_t)node * 64 + lane];
        float accx = wself * (float)v[0], accy = wself * (float)v[1];
        for (int e0 = beg; e0 < end; e0 += 64) {
            int rem = end - e0;
            int j = 0; float w = 0.f;
            if (lane < rem) {
                int2 ed = adj[e0 + lane];
                j = ed.x; w = __int_as_float(ed.y);
            }
            int cnt = rem < 64 ? rem : 64;
            for (int c = 0; c < cnt; c += 16) {
#pragma unroll
                for (int i = 0; i < 16; i++) {
                    int jj = __builtin_amdgcn_readlane(j, c + i);
                    float ww = __int_as_float(
                        __builtin_amdgcn_readlane(__float_as_int(w), c + i));
                    half2_t u = t2[(size_t)jj * 64 + lane];
                    accx += ww * (float)u[0];
                    accy += ww * (float)u[1];
                }
            }
        }
        float2 b = ((const float2*)bias)[lane];
        accx += b.x; accy += b.y;
        if (DOGELU) { accx = gelu_exact(accx); accy = gelu_exact(accy); }
        if (OUTF16) {
            half2_t o; o[0] = (_Float16)accx; o[1] = (_Float16)accy;
            ((half2_t*)outp)[(size_t)node * 64 + lane] = o;
        } else {
            float2 o; o.x = accx; o.y = accy;
            ((float2*)outp)[(size_t)node * 64 + lane] = o;
        }
    } else {  // F == 64
        float acc = wself * (float)t[(size_t)node * 64 + lane];
        for (int e0 = beg; e0 < end; e0 += 64) {
            int rem = end - e0;
            int j = 0; float w = 0.f;
            if (lane < rem) {
                int2 ed = adj[e0 + lane];
                j = ed.x; w = __int_as_float(ed.y);
            }
            int cnt = rem < 64 ? rem : 64;
            for (int c = 0; c < cnt; c += 16) {
#pragma unroll
                for (int i = 0; i < 16; i++) {
                    int jj = __builtin_amdgcn_readlane(j, c + i);
                    float ww = __int_as_float(
                        __builtin_amdgcn_readlane(__float_as_int(w), c + i));
                    acc += ww * (float)t[(size_t)jj * 64 + lane];
                }
            }
        }
        acc += bias[lane];
        if (DOGELU) acc = gelu_exact(acc);
        if (OUTF16) ((_Float16*)outp)[(size_t)node * 64 + lane] = (_Float16)acc;
        else        ((float*)outp)[(size_t)node * 64 + lane] = acc;
    }
}

// ---------------- launch ----------------

extern "C" void kernel_launch(void* const* d_in, const int* in_sizes, int n_in,
                              void* d_out, int out_size, void* d_ws, size_t ws_size,
                              hipStream_t stream) {
    const float* x  = (const float*)d_in[0];
    const int* edge = (const int*)d_in[1];
    const float* W1 = (const float*)d_in[2];
    const float* b1 = (const float*)d_in[3];
    const float* W2 = (const float*)d_in[4];
    const float* b2 = (const float*)d_in[5];
    const float* W3 = (const float*)d_in[6];
    const float* b3 = (const float*)d_in[7];
    float* out = (float*)d_out;

    const int N = in_sizes[0] / NDIN;       // 50000
    const int E = in_sizes[1] / 2;          // 800000
    const int* src = edge;
    const int* dst = edge + E;
    const int NB = (N + 255) / 256;         // 196 (must be <= 256)

    // workspace carve-out (256B aligned)
    char* p = (char*)d_ws;
    auto alloc = [&](size_t bytes) {
        char* q = p;
        p += (bytes + 255) & ~(size_t)255;
        return q;
    };
    int*       count    = (int*)alloc((size_t)N * 4);
    int*       rowptr   = (int*)alloc((size_t)(N + 1) * 4);
    int*       blocksum = (int*)alloc((size_t)NB * 4);
    int*       blockoff = (int*)alloc((size_t)NB * 4);
    int*       done     = (int*)alloc(256);
    float*     dinv     = (float*)alloc((size_t)N * 4);
    int2*      adj      = (int2*)alloc((size_t)E * 8);
    _Float16*  W1t      = (_Float16*)alloc((size_t)NHID * NDIN * 2);
    _Float16*  W2t      = (_Float16*)alloc((size_t)NHID * NHID * 2);
    _Float16*  W3t      = (_Float16*)alloc((size_t)NDOUT * NHID * 2);
    _Float16*  tbuf     = (_Float16*)alloc((size_t)N * NHID * 2);
    _Float16*  hbuf     = (_Float16*)alloc((size_t)N * NHID * 2);

    dim3 blk(256);
    int mtiles = (N + 63) / 64;             // 782
    int ntiles16 = (N + 15) / 16;           // 3125
    int eblocks = (E + 255) / 256;          // 3125
    int agg_blocks = (N + 3) / 4;           // 12500

    // 1. weight transpose+cast + zero count/done
    prep0_kernel<<<40 + NB, blk, 0, stream>>>(W1, W1t, W2, W2t, W3, W3t, count, done, N);
    // 2. degree count
    count_kernel<<<eblocks, blk, 0, stream>>>(dst, count, E);
    // 3. merged reduce + scan + dinv (spin on device-scope flag)
    reduce_scan_kernel<<<NB, blk, 0, stream>>>(count, blocksum, blockoff, rowptr,
                                               dinv, done, NB, N);
    // 4. CSR fill (standalone, zero LDS)
    fill_kernel<<<eblocks, blk, 0, stream>>>(src, dst, dinv, rowptr, count, adj, E);
    // 5. gemm1: x @ W1 -> tbuf
    gemm_mfma<128, false><<<mtiles, blk, 0, stream>>>(x, W1t, tbuf, N);
    // 6. agg1 (gelu,b1) fused with gemm2 -> hbuf   (16-row tiles: gather concurrency kept)
    agg_gemm16_kernel<128><<<ntiles16, blk, 0, stream>>>(tbuf, rowptr, adj, dinv, b1,
                                                         W2t, hbuf, N);
    // 7. agg2 (gelu,b2) fused with gemm3 -> tbuf (N x 64 fp16)
    agg_gemm16_kernel<64><<<ntiles16, blk, 0, stream>>>(hbuf, rowptr, adj, dinv, b2,
                                                        W3t, tbuf, N);
    // 8. final agg (no gelu, fp32 out)
    agg_kernel<64, false, false><<<agg_blocks, blk, 0, stream>>>(tbuf, rowptr, adj,
                                                                 dinv, b3, out, N);
}

// Round 3
// 268.126 us; speedup vs baseline: 1.2094x; 1.0797x over previous
//
#include <hip/hip_runtime.h>
#include <math.h>

#define NDIN 128
#define NHID 128
#define NDOUT 64

typedef _Float16 half2_t __attribute__((ext_vector_type(2)));
typedef _Float16 half4_t __attribute__((ext_vector_type(4)));
typedef _Float16 half8_t __attribute__((ext_vector_type(8)));
typedef float    float4v __attribute__((ext_vector_type(4)));

__device__ __forceinline__ float gelu_exact(float x) {
    return 0.5f * x * (1.0f + erff(x * 0.70710678118654752f));
}

// ---------------- prep0: 3x weight transpose+cast, zero count & done ----------------
// W[K][N] fp32 -> Wt[N][K] fp16, 32x32 LDS tiles.

__device__ void wtrans_tile(const float* __restrict__ W, _Float16* __restrict__ Wt,
                            int K, int N, int bx, int by) {
    __shared__ float tile[32][33];
    int tx = threadIdx.x & 31, ty = threadIdx.x >> 5;   // ty 0..7
    for (int i = 0; i < 32; i += 8) {
        int k = by * 32 + ty + i, nn = bx * 32 + tx;
        tile[ty + i][tx] = (k < K && nn < N) ? W[(size_t)k * N + nn] : 0.f;
    }
    __syncthreads();
    for (int i = 0; i < 32; i += 8) {
        int nn = bx * 32 + ty + i, k = by * 32 + tx;
        if (nn < N && k < K) Wt[(size_t)nn * K + k] = (_Float16)tile[tx][ty + i];
    }
}

// blocks: [0,16) W1; [16,32) W2; [32,40) W3; [40,40+NB) zero count (+done in block 40)
__global__ __launch_bounds__(256) void prep0_kernel(
    const float* __restrict__ W1, _Float16* __restrict__ W1t,
    const float* __restrict__ W2, _Float16* __restrict__ W2t,
    const float* __restrict__ W3, _Float16* __restrict__ W3t,
    int* __restrict__ count, int* __restrict__ done, int n) {
    int b = blockIdx.x;
    if (b < 16) {
        wtrans_tile(W1, W1t, NDIN, NHID, b & 3, b >> 2);
    } else if (b < 32) {
        wtrans_tile(W2, W2t, NHID, NHID, (b - 16) & 3, (b - 16) >> 2);
    } else if (b < 40) {
        wtrans_tile(W3, W3t, NHID, NDOUT, (b - 32) & 1, (b - 32) >> 1);
    } else {
        int z = b - 40;
        int i = z * 256 + threadIdx.x;
        if (i < n) count[i] = 0;
        if (z == 0 && threadIdx.x < 64) done[threadIdx.x] = 0;  // done[0]=arrive, done[1]=flag
    }
}

// ---------------- degree count + slot assignment ----------------
// R2 post-mortem: fill was 46 us, latency-bound on the atomicSub RETURN round trip.
// Assign the CSR slot HERE (atomicAdd already runs per edge); eslot write is coalesced.
// fill then needs no atomic at all.

__global__ void count_kernel(const int* __restrict__ dst, int* __restrict__ count,
                             int* __restrict__ eslot, int E) {
    int e = blockIdx.x * blockDim.x + threadIdx.x;
    if (e < E) eslot[e] = atomicAdd(&count[dst[e]], 1);
}

// ---------------- merged reduce + partial-scan + per-block scan + dinv ----------------
// Last-arriving block scans the partials and raises done[1]; other blocks spin on it
// (device-scope atomics only — safe under XCD non-coherence). Deadlock-free for ANY
// dispatch order: the scanner is the last block to finish phase 1, so whenever a block
// spins, its flag-setter is already executing. nb <= 256 required (nb = 196 here).

__global__ __launch_bounds__(256) void reduce_scan_kernel(
    const int* __restrict__ count, int* __restrict__ blocksum, int* __restrict__ blockoff,
    int* __restrict__ rowptr, float* __restrict__ dinv, int* __restrict__ done,
    int nb, int n) {
    __shared__ int s[256];
    __shared__ int flag;
    __shared__ int boff_s;
    int t = threadIdx.x;
    int i = blockIdx.x * 256 + t;
    int v = (i < n) ? count[i] : 0;
    s[t] = v;
    __syncthreads();
    for (int off = 128; off > 0; off >>= 1) {
        if (t < off) s[t] += s[t + off];
        __syncthreads();
    }
    if (t == 0) {
        atomicExch(&blocksum[blockIdx.x], s[0]);
        __threadfence();
        int old = atomicAdd(&done[0], 1);
        flag = (old == nb - 1) ? 1 : 0;
    }
    __syncthreads();
    if (flag) {  // last block: scan the per-block partials, publish offsets + flag
        __threadfence();
        int pv = (t < nb) ? atomicAdd(&blocksum[t], 0) : 0;
        s[t] = pv;
        __syncthreads();
        for (int off = 1; off < 256; off <<= 1) {
            int u = (t >= off) ? s[t - off] : 0;
            __syncthreads();
            s[t] += u;
            __syncthreads();
        }
        if (t < nb) atomicExch(&blockoff[t], s[t] - pv);   // exclusive
        if (t == 255) rowptr[n] = s[255];                  // grand total
        __threadfence();
        if (t == 0) atomicExch(&done[1], 1);
    } else if (t == 0) {
        while (atomicAdd(&done[1], 0) == 0) __builtin_amdgcn_s_sleep(2);
        __threadfence();
    }
    __syncthreads();
    if (t == 0) boff_s = atomicAdd(&blockoff[blockIdx.x], 0);  // atomic read: coherent
    s[t] = v;
    __syncthreads();
    for (int off = 1; off < 256; off <<= 1) {
        int u = (t >= off) ? s[t - off] : 0;
        __syncthreads();
        s[t] += u;
        __syncthreads();
    }
    if (i < n) {
        rowptr[i] = boff_s + s[t] - v;
        dinv[i] = rsqrtf((float)(v + 1));
    }
}

// ---------------- CSR fill (atomic-free: slot precomputed in count_kernel) ------------
// Chain per edge: coalesced src/dst/eslot reads -> rowptr[d] gather (200 KB, L2-hot,
// ~200 cy) -> dinv gathers (200 KB, L2-hot) -> one scattered 8B write (write-allocate
// ~51 MB is the floor). No atomic round trip.

__global__ void fill_kernel(const int* __restrict__ src, const int* __restrict__ dst,
                            const int* __restrict__ eslot, const float* __restrict__ dinv,
                            const int* __restrict__ rowptr, int2* __restrict__ adj, int E) {
    int e = blockIdx.x * blockDim.x + threadIdx.x;
    if (e >= E) return;
    int s = src[e], d = dst[e];
    int p = rowptr[d] + eslot[e];
    adj[p] = make_int2(s, __float_as_int(dinv[s] * dinv[d]));
}

// ---------------- fp16 MFMA GEMM (R0-proven): T = A @ Bt^T ----------------
// K fixed = 128, staged whole; 256 threads = 4 waves; wave w does rows [bm+16w,+16).

template <int BN, bool AF16>
__global__ __launch_bounds__(256) void gemm_mfma(
    const void* __restrict__ Aptr, const _Float16* __restrict__ Bt,
    _Float16* __restrict__ T, int M) {
    __shared__ _Float16 lds_a[64][136];
    __shared__ _Float16 lds_bt[BN][136];
    const int K = 128;
    int tid = threadIdx.x;
    int bm = blockIdx.x * 64;
    int wave = tid >> 6, lane = tid & 63;
    int m = lane & 15, quad = lane >> 4;

    if (AF16) {
        const _Float16* A = (const _Float16*)Aptr;
#pragma unroll
        for (int j = 0; j < 4; j++) {
            int c = tid + j * 256;
            int r = c >> 4, col = (c & 15) << 3;
            int grow = bm + r;
            uint4 v = make_uint4(0, 0, 0, 0);
            if (grow < M) v = *(const uint4*)(A + (size_t)grow * K + col);
            *(uint4*)&lds_a[r][col] = v;
        }
    } else {
        const float* A = (const float*)Aptr;
#pragma unroll
        for (int j = 0; j < 8; j++) {
            int c = tid + j * 256;
            int r = c >> 5, col = (c & 31) << 2;
            int grow = bm + r;
            float4 v = make_float4(0.f, 0.f, 0.f, 0.f);
            if (grow < M) v = *(const float4*)(A + (size_t)grow * K + col);
            half4_t h;
            h[0] = (_Float16)v.x; h[1] = (_Float16)v.y;
            h[2] = (_Float16)v.z; h[3] = (_Float16)v.w;
            *(half4_t*)&lds_a[r][col] = h;
        }
    }
    {
        const int chunks = BN * K / 8;
        for (int c = tid; c < chunks; c += 256) {
            int r = c >> 4, col = (c & 15) << 3;
            *(uint4*)&lds_bt[r][col] = *(const uint4*)(Bt + (size_t)r * K + col);
        }
    }
    __syncthreads();

    const int NT = BN / 16;
    float4v acc[NT];
#pragma unroll
    for (int nt = 0; nt < NT; nt++) acc[nt] = (float4v){0.f, 0.f, 0.f, 0.f};

    int arow = (wave << 4) + m;
#pragma unroll
    for (int kc = 0; kc < K; kc += 32) {
        half8_t a = *(const half8_t*)&lds_a[arow][kc + quad * 8];
#pragma unroll
        for (int nt = 0; nt < NT; nt++) {
            half8_t b = *(const half8_t*)&lds_bt[nt * 16 + m][kc + quad * 8];
            acc[nt] = __builtin_amdgcn_mfma_f32_16x16x32_f16(a, b, acc[nt], 0, 0, 0);
        }
    }
#pragma unroll
    for (int nt = 0; nt < NT; nt++) {
#pragma unroll
        for (int r = 0; r < 4; r++) {
            int grow = bm + (wave << 4) + (quad << 2) + r;
            if (grow < M) T[(size_t)grow * BN + nt * 16 + m] = (_Float16)acc[nt][r];
        }
    }
}

// ---------------- agg body for one node, F=128 (R4 readlane formulation) ----------------

__device__ __forceinline__ half2_t agg_node128(
    const half2_t* __restrict__ t2, const int* __restrict__ rowptr,
    const int2* __restrict__ adj, const float* __restrict__ dinv,
    const float* __restrict__ bias, int node, int lane) {
    float wself = dinv[node];
    wself *= wself;
    half2_t v = t2[(size_t)node * 64 + lane];
    float accx = wself * (float)v[0], accy = wself * (float)v[1];
    int beg = rowptr[node], end = rowptr[node + 1];
    for (int e0 = beg; e0 < end; e0 += 64) {
        int rem = end - e0;
        int j = 0; float w = 0.f;
        if (lane < rem) {
            int2 ed = adj[e0 + lane];
            j = ed.x; w = __int_as_float(ed.y);
        }
        int cnt = rem < 64 ? rem : 64;
        for (int c = 0; c < cnt; c += 16) {
#pragma unroll
            for (int i = 0; i < 16; i++) {
                int jj = __builtin_amdgcn_readlane(j, c + i);
                float ww = __int_as_float(
                    __builtin_amdgcn_readlane(__float_as_int(w), c + i));
                half2_t u = t2[(size_t)jj * 64 + lane];
                accx += ww * (float)u[0];
                accy += ww * (float)u[1];
            }
        }
    }
    float2 b = ((const float2*)bias)[lane];
    accx = gelu_exact(accx + b.x);
    accy = gelu_exact(accy + b.y);
    half2_t o; o[0] = (_Float16)accx; o[1] = (_Float16)accy;
    return o;
}

// ---------------- fused agg_i -> gemm_{i+1}, 16-row tiles (layer 2 only: A/B test) ----

template <int BN>
__global__ __launch_bounds__(256) void agg_gemm16_kernel(
    const _Float16* __restrict__ t, const int* __restrict__ rowptr,
    const int2* __restrict__ adj, const float* __restrict__ dinv,
    const float* __restrict__ bias, const _Float16* __restrict__ Bt,
    _Float16* __restrict__ T, int M) {
    __shared__ _Float16 lds_a[16][136];
    int tid = threadIdx.x;
    int wave = tid >> 6, lane = tid & 63;
    int bm = blockIdx.x * 16;
    const half2_t* t2 = (const half2_t*)t;
#pragma unroll 1
    for (int p = 0; p < 4; p++) {
        int r = (wave << 2) + p;
        int node = bm + r;
        half2_t o;
        o[0] = (_Float16)0.f; o[1] = (_Float16)0.f;
        if (node < M) o = agg_node128(t2, rowptr, adj, dinv, bias, node, lane);
        *(half2_t*)&lds_a[r][lane << 1] = o;   // 4B/lane: conflict-free
    }
    __syncthreads();

    int m = lane & 15, quad = lane >> 4;
    const int NT = BN / 64;                    // fragments per wave: 128->2, 64->1
    float4v acc[NT];
#pragma unroll
    for (int nt = 0; nt < NT; nt++) acc[nt] = (float4v){0.f, 0.f, 0.f, 0.f};
#pragma unroll
    for (int kc = 0; kc < 128; kc += 32) {
        half8_t a = *(const half8_t*)&lds_a[m][kc + quad * 8];
#pragma unroll
        for (int nt = 0; nt < NT; nt++) {
            int col = wave * (BN / 4) + nt * 16 + m;
            half8_t b = *(const half8_t*)&Bt[(size_t)col * 128 + kc + quad * 8];
            acc[nt] = __builtin_amdgcn_mfma_f32_16x16x32_f16(a, b, acc[nt], 0, 0, 0);
        }
    }
#pragma unroll
    for (int nt = 0; nt < NT; nt++) {
#pragma unroll
        for (int r = 0; r < 4; r++) {
            int grow = bm + (quad << 2) + r;
            int col = wave * (BN / 4) + nt * 16 + m;
            if (grow < M) T[(size_t)grow * BN + col] = (_Float16)acc[nt][r];
        }
    }
}

// ---------------- standalone aggregation (R4 readlane formulation, R0-proven) ----------
// out[i] = sum_e w_e*t[src_e] + dinv[i]^2*t[i] + b ; t fp16, fp32 accum.

template <int F, bool DOGELU, bool OUTF16>
__global__ __launch_bounds__(256) void agg_kernel(
    const _Float16* __restrict__ t, const int* __restrict__ rowptr,
    const int2* __restrict__ adj, const float* __restrict__ dinv,
    const float* __restrict__ bias, void* __restrict__ outp, int n) {
    int node = (int)((blockIdx.x * blockDim.x + threadIdx.x) >> 6);
    int lane = threadIdx.x & 63;
    if (node >= n) return;   // wave-uniform exit

    float wself = dinv[node];
    wself *= wself;
    int beg = rowptr[node];
    int end = rowptr[node + 1];

    if (F == 128) {
        const half2_t* t2 = (const half2_t*)t;
        half2_t v = t2[(size_t)node * 64 + lane];
        float accx = wself * (float)v[0], accy = wself * (float)v[1];
        for (int e0 = beg; e0 < end; e0 += 64) {
            int rem = end - e0;
            int j = 0; float w = 0.f;
            if (lane < rem) {
                int2 ed = adj[e0 + lane];
                j = ed.x; w = __int_as_float(ed.y);
            }
            int cnt = rem < 64 ? rem : 64;
            for (int c = 0; c < cnt; c += 16) {
#pragma unroll
                for (int i = 0; i < 16; i++) {
                    int jj = __builtin_amdgcn_readlane(j, c + i);
                    float ww = __int_as_float(
                        __builtin_amdgcn_readlane(__float_as_int(w), c + i));
                    half2_t u = t2[(size_t)jj * 64 + lane];
                    accx += ww * (float)u[0];
                    accy += ww * (float)u[1];
                }
            }
        }
        float2 b = ((const float2*)bias)[lane];
        accx += b.x; accy += b.y;
        if (DOGELU) { accx = gelu_exact(accx); accy = gelu_exact(accy); }
        if (OUTF16) {
            half2_t o; o[0] = (_Float16)accx; o[1] = (_Float16)accy;
            ((half2_t*)outp)[(size_t)node * 64 + lane] = o;
        } else {
            float2 o; o.x = accx; o.y = accy;
            ((float2*)outp)[(size_t)node * 64 + lane] = o;
        }
    } else {  // F == 64
        float acc = wself * (float)t[(size_t)node * 64 + lane];
        for (int e0 = beg; e0 < end; e0 += 64) {
            int rem = end - e0;
            int j = 0; float w = 0.f;
            if (lane < rem) {
                int2 ed = adj[e0 + lane];
                j = ed.x; w = __int_as_float(ed.y);
            }
            int cnt = rem < 64 ? rem : 64;
            for (int c = 0; c < cnt; c += 16) {
#pragma unroll
                for (int i = 0; i < 16; i++) {
                    int jj = __builtin_amdgcn_readlane(j, c + i);
                    float ww = __int_as_float(
                        __builtin_amdgcn_readlane(__float_as_int(w), c + i));
                    acc += ww * (float)t[(size_t)jj * 64 + lane];
                }
            }
        }
        acc += bias[lane];
        if (DOGELU) acc = gelu_exact(acc);
        if (OUTF16) ((_Float16*)outp)[(size_t)node * 64 + lane] = (_Float16)acc;
        else        ((float*)outp)[(size_t)node * 64 + lane] = acc;
    }
}

// ---------------- launch ----------------

extern "C" void kernel_launch(void* const* d_in, const int* in_sizes, int n_in,
                              void* d_out, int out_size, void* d_ws, size_t ws_size,
                              hipStream_t stream) {
    const float* x  = (const float*)d_in[0];
    const int* edge = (const int*)d_in[1];
    const float* W1 = (const float*)d_in[2];
    const float* b1 = (const float*)d_in[3];
    const float* W2 = (const float*)d_in[4];
    const float* b2 = (const float*)d_in[5];
    const float* W3 = (const float*)d_in[6];
    const float* b3 = (const float*)d_in[7];
    float* out = (float*)d_out;

    const int N = in_sizes[0] / NDIN;       // 50000
    const int E = in_sizes[1] / 2;          // 800000
    const int* src = edge;
    const int* dst = edge + E;
    const int NB = (N + 255) / 256;         // 196 (must be <= 256)

    // workspace carve-out (256B aligned)
    char* p = (char*)d_ws;
    auto alloc = [&](size_t bytes) {
        char* q = p;
        p += (bytes + 255) & ~(size_t)255;
        return q;
    };
    int*       count    = (int*)alloc((size_t)N * 4);
    int*       rowptr   = (int*)alloc((size_t)(N + 1) * 4);
    int*       blocksum = (int*)alloc((size_t)NB * 4);
    int*       blockoff = (int*)alloc((size_t)NB * 4);
    int*       done     = (int*)alloc(256);
    float*     dinv     = (float*)alloc((size_t)N * 4);
    int*       eslot    = (int*)alloc((size_t)E * 4);
    int2*      adj      = (int2*)alloc((size_t)E * 8);
    _Float16*  W1t      = (_Float16*)alloc((size_t)NHID * NDIN * 2);
    _Float16*  W2t      = (_Float16*)alloc((size_t)NHID * NHID * 2);
    _Float16*  W3t      = (_Float16*)alloc((size_t)NDOUT * NHID * 2);
    _Float16*  tbuf     = (_Float16*)alloc((size_t)N * NHID * 2);
    _Float16*  hbuf     = (_Float16*)alloc((size_t)N * NHID * 2);

    dim3 blk(256);
    int mtiles = (N + 63) / 64;             // 782
    int ntiles16 = (N + 15) / 16;           // 3125
    int eblocks = (E + 255) / 256;          // 3125
    int agg_blocks = (N + 3) / 4;           // 12500

    // 1. weight transpose+cast + zero count/done
    prep0_kernel<<<40 + NB, blk, 0, stream>>>(W1, W1t, W2, W2t, W3, W3t, count, done, N);
    // 2. degree count + slot assignment (coalesced eslot write)
    count_kernel<<<eblocks, blk, 0, stream>>>(dst, count, eslot, E);
    // 3. merged reduce + scan + dinv (spin on device-scope flag)
    reduce_scan_kernel<<<NB, blk, 0, stream>>>(count, blocksum, blockoff, rowptr,
                                               dinv, done, NB, N);
    // 4. CSR fill (atomic-free)
    fill_kernel<<<eblocks, blk, 0, stream>>>(src, dst, eslot, dinv, rowptr, adj, E);
    // 5. gemm1: x @ W1 -> tbuf
    gemm_mfma<128, false><<<mtiles, blk, 0, stream>>>(x, W1t, tbuf, N);
    // 6. layer 2 FUSED: agg1 (gelu,b1) + gemm2 -> hbuf   [A/B arm 1]
    agg_gemm16_kernel<128><<<ntiles16, blk, 0, stream>>>(tbuf, rowptr, adj, dinv, b1,
                                                         W2t, hbuf, N);
    // 7. layer 3 STANDALONE: agg2 (gelu,b2) -> tbuf, then gemm3 -> hbuf  [A/B arm 2]
    agg_kernel<128, true, true><<<agg_blocks, blk, 0, stream>>>(hbuf, rowptr, adj,
                                                                dinv, b2, tbuf, N);
    gemm_mfma<64, true><<<mtiles, blk, 0, stream>>>(tbuf, W3t, hbuf, N);
    // 8. final agg (no gelu, fp32 out)
    agg_kernel<64, false, false><<<agg_blocks, blk, 0, stream>>>(hbuf, rowptr, adj,
                                                                 dinv, b3, out, N);
}